// Round 5
// baseline (406.673 us; speedup 1.0000x reference)
//
#include <hip/hip_runtime.h>

#define NIMG 128
#define NOBJ 32
#define NPRI 8732
#define NCLS 21
#define NP (NIMG * NPRI)
#define SPLIT 16
#define CHUNK ((NPRI + SPLIT - 1) / SPLIT)   // 546
#define CAP 2048

static_assert(NP % 256 == 0, "NP must be divisible by 256");

// ---------------- helpers ----------------

__device__ __forceinline__ int blockReduceAllInt(int v, int* sred) {
  #pragma unroll
  for (int off = 32; off > 0; off >>= 1) v += __shfl_down(v, off);
  const int tid = threadIdx.x;
  if ((tid & 63) == 0) sred[tid >> 6] = v;
  __syncthreads();
  v = sred[0] + sred[1] + sred[2] + sred[3];
  __syncthreads();
  return v;
}

__device__ __forceinline__ double blockReduceAllDouble(double v, double* sredd) {
  #pragma unroll
  for (int off = 32; off > 0; off >>= 1) v += __shfl_down(v, off);
  const int tid = threadIdx.x;
  if ((tid & 63) == 0) sredd[tid >> 6] = v;
  __syncthreads();
  v = sredd[0] + sredd[1] + sredd[2] + sredd[3];
  __syncthreads();
  return v;
}

// ---------------- kernels ----------------

// Jaccard over one (image, prior-chunk). grid = (SPLIT, NIMG) = 2048 blocks.
__global__ __launch_bounds__(256) void k_overlap(
    const float* __restrict__ boxes, const float* __restrict__ priors,
    float* __restrict__ ovl_buf, unsigned char* __restrict__ obj_buf,
    float* __restrict__ part_v, int* __restrict__ part_p)
{
  const int s = blockIdx.x;
  const int i = blockIdx.y;
  const int tid = threadIdx.x;
  __shared__ float4 sbox[NOBJ];
  __shared__ float sarea[NOBJ];
  __shared__ float s_cand_v[NOBJ][4];
  __shared__ int   s_cand_p[NOBJ][4];

  if (tid < NOBJ) {
    const float4 b = ((const float4*)boxes)[i * NOBJ + tid];
    sbox[tid] = b;
    sarea[tid] = (b.z - b.x) * (b.w - b.y);
  }
  __syncthreads();

  float obv[NOBJ]; int obp[NOBJ];
  #pragma unroll
  for (int o = 0; o < NOBJ; ++o) { obv[o] = -1.0f; obp[o] = 0x7fffffff; }

  const int base = s * CHUNK;
  const int lim = (base + CHUNK < NPRI) ? base + CHUNK : NPRI;
  for (int p = base + tid; p < lim; p += 256) {
    const float4 pr = ((const float4*)priors)[p];
    const float px1 = pr.x - pr.z * 0.5f, py1 = pr.y - pr.w * 0.5f;
    const float px2 = pr.x + pr.z * 0.5f, py2 = pr.y + pr.w * 0.5f;
    const float parea = (px2 - px1) * (py2 - py1);
    float bestv = -1.0f; int besto = 0;
    #pragma unroll
    for (int o = 0; o < NOBJ; ++o) {
      const float4 b = sbox[o];
      const float ltx = fmaxf(b.x, px1), lty = fmaxf(b.y, py1);
      const float rbx = fminf(b.z, px2), rby = fminf(b.w, py2);
      const float iw = fmaxf(rbx - ltx, 0.0f), ih = fmaxf(rby - lty, 0.0f);
      const float inter = iw * ih;
      const float ovl = inter / (sarea[o] + parea - inter);
      if (ovl > bestv) { bestv = ovl; besto = o; }       // first-wins (strict >)
      if (ovl > obv[o]) { obv[o] = ovl; obp[o] = p; }    // lowest p wins in-thread
    }
    ovl_buf[i * NPRI + p] = bestv;
    obj_buf[i * NPRI + p] = (unsigned char)besto;
  }

  // cross-lane per-object argmax: butterfly, comparator (v desc, p asc) —
  // associative+commutative, preserves jnp.argmax lowest-index ties.
  #pragma unroll
  for (int o = 0; o < NOBJ; ++o) {
    float v = obv[o]; int p = obp[o];
    #pragma unroll
    for (int m = 32; m > 0; m >>= 1) {
      const float ov = __shfl_xor(v, m);
      const int   op = __shfl_xor(p, m);
      if (ov > v || (ov == v && op < p)) { v = ov; p = op; }
    }
    if ((tid & 63) == 0) { s_cand_v[o][tid >> 6] = v; s_cand_p[o][tid >> 6] = p; }
  }
  __syncthreads();
  if (tid < NOBJ) {
    float bv = -1.0f; int bp = 0x7fffffff;
    #pragma unroll
    for (int j = 0; j < 4; ++j) {
      const float v = s_cand_v[tid][j]; const int pp = s_cand_p[tid][j];
      if (v > bv || (v == bv && pp < bp)) { bv = v; bp = pp; }
    }
    part_v[(i * SPLIT + s) * NOBJ + tid] = bv;
    part_p[(i * SPLIT + s) * NOBJ + tid] = bp;
  }
}

// Combine partial argmaxes; force-match via LDS map; threshold+label+pack.
__global__ __launch_bounds__(256) void k_fin(
    const float* __restrict__ part_v, const int* __restrict__ part_p,
    const int* __restrict__ labels, const float* __restrict__ ovl_buf,
    const unsigned char* __restrict__ obj_buf, int* __restrict__ packed_buf,
    int* __restrict__ n_pos)
{
  const int i = blockIdx.x;
  const int tid = threadIdx.x;
  __shared__ int s_forced[NPRI];   // forced object per prior, -1 = none
  __shared__ int slab[NOBJ];
  __shared__ int s_red[4];

  for (int p = tid; p < NPRI; p += 256) s_forced[p] = -1;
  if (tid < NOBJ) slab[tid] = labels[i * NOBJ + tid];
  __syncthreads();

  if (tid < NOBJ) {
    float bv = -1.0f; int bp = 0x7fffffff;
    #pragma unroll
    for (int s = 0; s < SPLIT; ++s) {
      const float v = part_v[(i * SPLIT + s) * NOBJ + tid];
      const int  pp = part_p[(i * SPLIT + s) * NOBJ + tid];
      if (v > bv || (v == bv && pp < bp)) { bv = v; bp = pp; }
    }
    // scatter updates apply in ascending object order, last (=highest) wins:
    atomicMax(&s_forced[bp], tid);
  }
  __syncthreads();

  int cnt = 0;
  for (int p = tid; p < NPRI; p += 256) {
    float v = ovl_buf[i * NPRI + p];
    int o = obj_buf[i * NPRI + p];
    const int f = s_forced[p];
    if (f >= 0) { v = 1.0f; o = f; }
    const int c = (v < 0.5f) ? 0 : slab[o];
    packed_buf[i * NPRI + p] = o | (c << 8);
    cnt += (c != 0) ? 1 : 0;
  }
  cnt = blockReduceAllInt(cnt, s_red);
  if (tid == 0) n_pos[i] = cnt;
}

// CE for every prior + smooth-L1 on positives; per-block double2 partial.
__global__ __launch_bounds__(256) void k_celoc(
    const float* __restrict__ scores, const float* __restrict__ locs,
    const float* __restrict__ boxes, const float* __restrict__ priors,
    const int* __restrict__ packed_buf, float* __restrict__ negce,
    double2* __restrict__ cel_part)
{
  __shared__ float s_sc[256 * NCLS];
  __shared__ double sredd[8];
  const int tid = threadIdx.x;
  const long base = (long)blockIdx.x * 256;

  const float4* gsc4 = (const float4*)(scores + base * NCLS);
  float4* s4 = (float4*)s_sc;
  for (int j = tid; j < 256 * NCLS / 4; j += 256) s4[j] = gsc4[j];
  __syncthreads();

  const int idx = (int)base + tid;
  const float* s = &s_sc[tid * NCLS];   // stride 21: 2 lanes/bank, conflict-free
  float mx = s[0];
  #pragma unroll
  for (int c = 1; c < NCLS; ++c) mx = fmaxf(mx, s[c]);
  float se = 0.0f;
  #pragma unroll
  for (int c = 0; c < NCLS; ++c) se += expf(s[c] - mx);
  const float lse = mx + logf(se);

  const int packed = packed_buf[idx];
  const int cls = packed >> 8;
  const float ce = lse - s[cls];
  const bool pos = (cls != 0);
  negce[idx] = pos ? 0.0f : ce;

  float cep = pos ? ce : 0.0f;
  float ls = 0.0f;
  if (pos) {
    const int i = idx / NPRI;
    const int p = idx - i * NPRI;
    const int o = packed & 0xff;
    const float4 b = ((const float4*)boxes)[i * NOBJ + o];
    const float4 pr = ((const float4*)priors)[p];
    const float cx = (b.x + b.z) * 0.5f, cy = (b.y + b.w) * 0.5f;
    const float w = b.z - b.x, h = b.w - b.y;
    const float g0 = (cx - pr.x) / (pr.z / 10.0f);
    const float g1 = (cy - pr.y) / (pr.w / 10.0f);
    const float g2 = logf(w / pr.z) * 5.0f;
    const float g3 = logf(h / pr.w) * 5.0f;
    const float4 pl = ((const float4*)locs)[idx];
    const float d0 = pl.x - g0, d1 = pl.y - g1, d2 = pl.z - g2, d3 = pl.w - g3;
    const float a0 = fabsf(d0), a1 = fabsf(d1), a2 = fabsf(d2), a3 = fabsf(d3);
    ls += (a0 < 1.0f) ? 0.5f * d0 * d0 : a0 - 0.5f;
    ls += (a1 < 1.0f) ? 0.5f * d1 * d1 : a1 - 0.5f;
    ls += (a2 < 1.0f) ? 0.5f * d2 * d2 : a2 - 0.5f;
    ls += (a3 < 1.0f) ? 0.5f * d3 * d3 : a3 - 0.5f;
  }

  #pragma unroll
  for (int off = 32; off > 0; off >>= 1) {
    cep += __shfl_down(cep, off);
    ls  += __shfl_down(ls, off);
  }
  if ((tid & 63) == 0) { sredd[tid >> 6] = (double)cep; sredd[4 + (tid >> 6)] = (double)ls; }
  __syncthreads();
  if (tid == 0) {
    double2 v;
    v.x = sredd[0] + sredd[1] + sredd[2] + sredd[3];
    v.y = sredd[4] + sredd[5] + sredd[6] + sredd[7];
    cel_part[blockIdx.x] = v;
  }
}

// Per-image sum of top-(3*n_pos) negative CEs: histogram radix-select (exact).
__global__ __launch_bounds__(256) void k_hardneg(
    const float* __restrict__ negce, const int* __restrict__ n_pos,
    double* __restrict__ hard_out)
{
  __shared__ unsigned s_bits[NPRI];     // 34928 B
  __shared__ unsigned s_hist[2048];     // 8192 B
  __shared__ unsigned s_comp[CAP];      // 8192 B
  __shared__ int s_scan[256];
  __shared__ int s_red[4];
  __shared__ double s_redd[4];
  __shared__ int s_sel[3];              // B, kp, compact counter
  const int i = blockIdx.x;
  const int tid = threadIdx.x;

  const uint4* g4 = (const uint4*)(negce + i * NPRI);
  uint4* s4 = (uint4*)s_bits;
  for (int j = tid; j < NPRI / 4; j += 256) s4[j] = g4[j];
  for (int j = tid; j < 2048; j += 256) s_hist[j] = 0u;
  __syncthreads();

  const int k = 3 * n_pos[i];
  if (k <= 0) { if (tid == 0) hard_out[i] = 0.0; return; }

  if (k >= NPRI) {   // top-k covers everything (positives are 0 in negce)
    double s = 0.0;
    for (int p = tid; p < NPRI; p += 256) s += (double)__uint_as_float(s_bits[p]);
    s = blockReduceAllDouble(s, s_redd);
    if (tid == 0) hard_out[i] = s;
    return;
  }

  // Phase A: 11-bit histogram (nonneg floats: top bits monotone in value)
  for (int p = tid; p < NPRI; p += 256) atomicAdd(&s_hist[s_bits[p] >> 20], 1u);
  __syncthreads();

  // Phase B: suffix scan over 256 groups of 8 bins -> find bin B of k-th value
  int sT = 0;
  #pragma unroll
  for (int j = 0; j < 8; ++j) sT += (int)s_hist[tid * 8 + j];
  s_scan[tid] = sT;
  __syncthreads();
  for (int off = 1; off < 256; off <<= 1) {
    const int add = (tid + off < 256) ? s_scan[tid + off] : 0;
    __syncthreads();
    s_scan[tid] += add;
    __syncthreads();
  }
  const int above_group = (tid + 1 < 256) ? s_scan[tid + 1] : 0;
  {
    int cnt_gt = above_group;
    int foundB = -1, fkp = 0;
    #pragma unroll
    for (int j = 7; j >= 0; --j) {
      const int b = tid * 8 + j;
      const int h = (int)s_hist[b];
      if (foundB < 0 && cnt_gt < k && k <= cnt_gt + h) { foundB = b; fkp = k - cnt_gt; }
      cnt_gt += h;
    }
    if (foundB >= 0) { s_sel[0] = foundB; s_sel[1] = fkp; }  // exactly one thread
  }
  if (tid == 0) s_sel[2] = 0;
  __syncthreads();
  const int B = s_sel[0];
  const int kp = s_sel[1];
  const int m = (int)s_hist[B];

  // Phase C: sum bins > B, compact bin-B elements (if they fit)
  double sg = 0.0;
  for (int p = tid; p < NPRI; p += 256) {
    const unsigned b = s_bits[p];
    const int bb = (int)(b >> 20);
    if (bb > B) sg += (double)__uint_as_float(b);
    else if (bb == B && m <= CAP) s_comp[atomicAdd(&s_sel[2], 1)] = b;
  }
  __syncthreads();

  unsigned prefix = ((unsigned)B) << 20;
  bool exact = false;
  if (m <= CAP) {
    for (int bit = 19; bit >= 0 && !exact; --bit) {
      const unsigned cand = prefix | (1u << bit);
      int cnt = 0;
      for (int p = tid; p < m; p += 256) cnt += (s_comp[p] >= cand) ? 1 : 0;
      cnt = blockReduceAllInt(cnt, s_red);
      if (cnt >= kp) prefix = cand;
      if (cnt == kp) exact = true;
    }
    int cg = 0;
    if (exact) {
      for (int p = tid; p < m; p += 256) {
        const unsigned b = s_comp[p];
        if (b >= prefix) sg += (double)__uint_as_float(b);
      }
    } else {
      for (int p = tid; p < m; p += 256) {
        const unsigned b = s_comp[p];
        if (b > prefix) { sg += (double)__uint_as_float(b); cg++; }
      }
    }
    sg = blockReduceAllDouble(sg, s_redd);
    cg = blockReduceAllInt(cg, s_red);
    if (tid == 0)
      hard_out[i] = exact ? sg
                          : sg + (double)(kp - cg) * (double)__uint_as_float(prefix);
  } else {
    // rare fallback: masked bit-search over full LDS array
    for (int bit = 19; bit >= 0 && !exact; --bit) {
      const unsigned cand = prefix | (1u << bit);
      int cnt = 0;
      for (int p = tid; p < NPRI; p += 256) {
        const unsigned b = s_bits[p];
        cnt += ((int)(b >> 20) == B && b >= cand) ? 1 : 0;
      }
      cnt = blockReduceAllInt(cnt, s_red);
      if (cnt >= kp) prefix = cand;
      if (cnt == kp) exact = true;
    }
    int cg = 0;
    for (int p = tid; p < NPRI; p += 256) {
      const unsigned b = s_bits[p];
      if ((int)(b >> 20) != B) continue;
      if (exact) { if (b >= prefix) sg += (double)__uint_as_float(b); }
      else if (b > prefix) { sg += (double)__uint_as_float(b); cg++; }
    }
    sg = blockReduceAllDouble(sg, s_redd);
    cg = blockReduceAllInt(cg, s_red);
    if (tid == 0)
      hard_out[i] = exact ? sg
                          : sg + (double)(kp - cg) * (double)__uint_as_float(prefix);
  }
}

__global__ __launch_bounds__(256) void k_final(
    const double2* __restrict__ cel_part, const double* __restrict__ hard_out,
    const int* __restrict__ n_pos, float* __restrict__ out)
{
  __shared__ double s_redd[4];
  __shared__ int s_red[4];
  const int tid = threadIdx.x;
  double ce = 0.0, ls = 0.0, hn = 0.0; int tp = 0;
  for (int j = tid; j < NP / 256; j += 256) { const double2 v = cel_part[j]; ce += v.x; ls += v.y; }
  for (int j = tid; j < NIMG; j += 256) { hn += hard_out[j]; tp += n_pos[j]; }
  ce = blockReduceAllDouble(ce, s_redd);
  ls = blockReduceAllDouble(ls, s_redd);
  hn = blockReduceAllDouble(hn, s_redd);
  tp = blockReduceAllInt(tp, s_red);
  if (tid == 0) {
    const double T = (double)tp;
    out[0] = (float)((ce + hn) / T + ls / (T * 4.0));
  }
}

// ---------------- launch ----------------

extern "C" void kernel_launch(void* const* d_in, const int* in_sizes, int n_in,
                              void* d_out, int out_size, void* d_ws, size_t ws_size,
                              hipStream_t stream)
{
  const float* locs   = (const float*)d_in[0];  // (N, P, 4)
  const float* scores = (const float*)d_in[1];  // (N, P, 21)
  const float* boxes  = (const float*)d_in[2];  // (N, 32, 4)
  const int*   labels = (const int*)d_in[3];    // (N, 32)
  const float* priors = (const float*)d_in[4];  // (P, 4)
  float* out = (float*)d_out;

  char* ws = (char*)d_ws;
  size_t off = 0;
  float*  negce  = (float*)(ws + off);  off += (size_t)NP * 4;
  int*    packed = (int*)(ws + off);    off += (size_t)NP * 4;
  float*  ovl    = (float*)(ws + off);  off += (size_t)NP * 4;
  unsigned char* obj = (unsigned char*)(ws + off); off += (size_t)NP;
  off = (off + 255) & ~(size_t)255;
  float*  part_v = (float*)(ws + off);  off += (size_t)NIMG * SPLIT * NOBJ * 4;
  int*    part_p = (int*)(ws + off);    off += (size_t)NIMG * SPLIT * NOBJ * 4;
  double2* cel_part = (double2*)(ws + off); off += (size_t)(NP / 256) * 16;
  double*  hard_out = (double*)(ws + off);  off += (size_t)NIMG * 8;
  int*     n_pos    = (int*)(ws + off);     off += (size_t)NIMG * 4;

  hipLaunchKernelGGL(k_overlap, dim3(SPLIT, NIMG), dim3(256), 0, stream,
                     boxes, priors, ovl, obj, part_v, part_p);
  hipLaunchKernelGGL(k_fin, dim3(NIMG), dim3(256), 0, stream,
                     part_v, part_p, labels, ovl, obj, packed, n_pos);
  hipLaunchKernelGGL(k_celoc, dim3(NP / 256), dim3(256), 0, stream,
                     scores, locs, boxes, priors, packed, negce, cel_part);
  hipLaunchKernelGGL(k_hardneg, dim3(NIMG), dim3(256), 0, stream,
                     negce, n_pos, hard_out);
  hipLaunchKernelGGL(k_final, dim3(1), dim3(256), 0, stream,
                     cel_part, hard_out, n_pos, out);
}

// Round 10
// 271.478 us; speedup vs baseline: 1.4980x; 1.4980x over previous
//
#include <hip/hip_runtime.h>

#define NIMG 128
#define NOBJ 32
#define NPRI 8732
#define NCLS 21
#define NP (NIMG * NPRI)
#define PCHUNKS ((NPRI + 255) / 256)   // 35
#define CAP 2048

static_assert(NP % 256 == 0, "NP must be divisible by 256");

// ---------------- helpers ----------------

__device__ __forceinline__ int blockReduceAllInt(int v, int* sred) {
  #pragma unroll
  for (int off = 32; off > 0; off >>= 1) v += __shfl_down(v, off);
  const int tid = threadIdx.x;
  if ((tid & 63) == 0) sred[tid >> 6] = v;
  __syncthreads();
  v = sred[0] + sred[1] + sred[2] + sred[3];
  __syncthreads();
  return v;
}

__device__ __forceinline__ double blockReduceAllDouble(double v, double* sredd) {
  #pragma unroll
  for (int off = 32; off > 0; off >>= 1) v += __shfl_down(v, off);
  const int tid = threadIdx.x;
  if ((tid & 63) == 0) sredd[tid >> 6] = v;
  __syncthreads();
  v = sredd[0] + sredd[1] + sredd[2] + sredd[3];
  __syncthreads();
  return v;
}

// ---------------- kernels ----------------

// Per-(image,prior) best object. Thread = one prior; tiny state, no arrays.
// grid = (PCHUNKS, NIMG). IoU expression order matches reference exactly.
__global__ __launch_bounds__(256) void k_bestobj(
    const float* __restrict__ boxes, const float* __restrict__ priors,
    float* __restrict__ ovl_buf, unsigned char* __restrict__ obj_buf)
{
  const int i = blockIdx.y;
  const int tid = threadIdx.x;
  __shared__ float sx1[NOBJ], sy1[NOBJ], sx2[NOBJ], sy2[NOBJ], sar[NOBJ];
  if (tid < NOBJ) {
    const float4 b = ((const float4*)boxes)[i * NOBJ + tid];
    sx1[tid] = b.x; sy1[tid] = b.y; sx2[tid] = b.z; sy2[tid] = b.w;
    sar[tid] = (b.z - b.x) * (b.w - b.y);
  }
  __syncthreads();

  const int p = blockIdx.x * 256 + tid;
  if (p >= NPRI) return;

  const float4 pr = ((const float4*)priors)[p];
  const float px1 = pr.x - pr.z * 0.5f, py1 = pr.y - pr.w * 0.5f;
  const float px2 = pr.x + pr.z * 0.5f, py2 = pr.y + pr.w * 0.5f;
  const float parea = (px2 - px1) * (py2 - py1);

  float bestv = -1.0f; int besto = 0;
  #pragma unroll
  for (int o = 0; o < NOBJ; ++o) {
    const float ltx = fmaxf(sx1[o], px1), lty = fmaxf(sy1[o], py1);
    const float rbx = fminf(sx2[o], px2), rby = fminf(sy2[o], py2);
    const float iw = fmaxf(rbx - ltx, 0.0f), ih = fmaxf(rby - lty, 0.0f);
    const float inter = iw * ih;
    const float ovl = inter / (sar[o] + parea - inter);
    if (ovl > bestv) { bestv = ovl; besto = o; }   // first (lowest o) wins ties
  }
  ovl_buf[i * NPRI + p] = bestv;
  obj_buf[i * NPRI + p] = (unsigned char)besto;
}

// Per-(image,object) best prior. One WAVE per (i,o); 4 waves of a block share
// an image for L1 reuse of the prior array. One butterfly per wave total.
__global__ __launch_bounds__(256) void k_bestpri(
    const float* __restrict__ boxes, const float* __restrict__ priors,
    int* __restrict__ pfo)
{
  const int wid = threadIdx.x >> 6, lane = threadIdx.x & 63;
  const int i = blockIdx.x >> 3;
  const int o = ((blockIdx.x & 7) << 2) | wid;

  const float4 b = ((const float4*)boxes)[i * NOBJ + o];
  const float bx1 = b.x, by1 = b.y, bx2 = b.z, by2 = b.w;
  const float barea = (bx2 - bx1) * (by2 - by1);

  float bv = -1.0f; int bp = 0x7fffffff;
  for (int p = lane; p < NPRI; p += 64) {     // ascending p: lowest wins ties
    const float4 pr = ((const float4*)priors)[p];
    const float px1 = pr.x - pr.z * 0.5f, py1 = pr.y - pr.w * 0.5f;
    const float px2 = pr.x + pr.z * 0.5f, py2 = pr.y + pr.w * 0.5f;
    const float parea = (px2 - px1) * (py2 - py1);
    const float ltx = fmaxf(bx1, px1), lty = fmaxf(by1, py1);
    const float rbx = fminf(bx2, px2), rby = fminf(by2, py2);
    const float iw = fmaxf(rbx - ltx, 0.0f), ih = fmaxf(rby - lty, 0.0f);
    const float inter = iw * ih;
    const float ovl = inter / (barea + parea - inter);
    if (ovl > bv) { bv = ovl; bp = p; }
  }
  #pragma unroll
  for (int m = 32; m > 0; m >>= 1) {   // comparator (v desc, p asc): order-safe
    const float ov = __shfl_xor(bv, m);
    const int   op = __shfl_xor(bp, m);
    if (ov > bv || (ov == bv && op < bp)) { bv = ov; bp = op; }
  }
  if (lane == 0) pfo[i * NOBJ + o] = bp;
}

// Force-match via LDS map; threshold+label+pack; count positives.
__global__ __launch_bounds__(256) void k_fin(
    const int* __restrict__ pfo, const int* __restrict__ labels,
    const float* __restrict__ ovl_buf, const unsigned char* __restrict__ obj_buf,
    int* __restrict__ packed_buf, int* __restrict__ n_pos)
{
  const int i = blockIdx.x;
  const int tid = threadIdx.x;
  __shared__ int s_forced[NPRI];   // forced object per prior, -1 = none
  __shared__ int slab[NOBJ];
  __shared__ int s_red[4];

  for (int p = tid; p < NPRI; p += 256) s_forced[p] = -1;
  if (tid < NOBJ) slab[tid] = labels[i * NOBJ + tid];
  __syncthreads();

  if (tid < NOBJ) {
    // scatter updates apply in ascending object order, last (=highest) wins:
    atomicMax(&s_forced[pfo[i * NOBJ + tid]], tid);
  }
  __syncthreads();

  int cnt = 0;
  for (int p = tid; p < NPRI; p += 256) {
    float v = ovl_buf[i * NPRI + p];
    int o = obj_buf[i * NPRI + p];
    const int f = s_forced[p];
    if (f >= 0) { v = 1.0f; o = f; }
    const int c = (v < 0.5f) ? 0 : slab[o];
    packed_buf[i * NPRI + p] = o | (c << 8);
    cnt += (c != 0) ? 1 : 0;
  }
  cnt = blockReduceAllInt(cnt, s_red);
  if (tid == 0) n_pos[i] = cnt;
}

// CE for every prior + smooth-L1 on positives; per-block double2 partial.
__global__ __launch_bounds__(256) void k_celoc(
    const float* __restrict__ scores, const float* __restrict__ locs,
    const float* __restrict__ boxes, const float* __restrict__ priors,
    const int* __restrict__ packed_buf, float* __restrict__ negce,
    double2* __restrict__ cel_part)
{
  __shared__ float s_sc[256 * NCLS];
  __shared__ double sredd[8];
  const int tid = threadIdx.x;
  const long base = (long)blockIdx.x * 256;

  const float4* gsc4 = (const float4*)(scores + base * NCLS);
  float4* s4 = (float4*)s_sc;
  for (int j = tid; j < 256 * NCLS / 4; j += 256) s4[j] = gsc4[j];
  __syncthreads();

  const int idx = (int)base + tid;
  const float* s = &s_sc[tid * NCLS];   // stride 21: 2 lanes/bank, conflict-free
  float mx = s[0];
  #pragma unroll
  for (int c = 1; c < NCLS; ++c) mx = fmaxf(mx, s[c]);
  float se = 0.0f;
  #pragma unroll
  for (int c = 0; c < NCLS; ++c) se += expf(s[c] - mx);
  const float lse = mx + logf(se);

  const int packed = packed_buf[idx];
  const int cls = packed >> 8;
  const float ce = lse - s[cls];
  const bool pos = (cls != 0);
  negce[idx] = pos ? 0.0f : ce;

  float cep = pos ? ce : 0.0f;
  float ls = 0.0f;
  if (pos) {
    const int i = idx / NPRI;
    const int p = idx - i * NPRI;
    const int o = packed & 0xff;
    const float4 b = ((const float4*)boxes)[i * NOBJ + o];
    const float4 pr = ((const float4*)priors)[p];
    const float cx = (b.x + b.z) * 0.5f, cy = (b.y + b.w) * 0.5f;
    const float w = b.z - b.x, h = b.w - b.y;
    const float g0 = (cx - pr.x) / (pr.z / 10.0f);
    const float g1 = (cy - pr.y) / (pr.w / 10.0f);
    const float g2 = logf(w / pr.z) * 5.0f;
    const float g3 = logf(h / pr.w) * 5.0f;
    const float4 pl = ((const float4*)locs)[idx];
    const float d0 = pl.x - g0, d1 = pl.y - g1, d2 = pl.z - g2, d3 = pl.w - g3;
    const float a0 = fabsf(d0), a1 = fabsf(d1), a2 = fabsf(d2), a3 = fabsf(d3);
    ls += (a0 < 1.0f) ? 0.5f * d0 * d0 : a0 - 0.5f;
    ls += (a1 < 1.0f) ? 0.5f * d1 * d1 : a1 - 0.5f;
    ls += (a2 < 1.0f) ? 0.5f * d2 * d2 : a2 - 0.5f;
    ls += (a3 < 1.0f) ? 0.5f * d3 * d3 : a3 - 0.5f;
  }

  #pragma unroll
  for (int off = 32; off > 0; off >>= 1) {
    cep += __shfl_down(cep, off);
    ls  += __shfl_down(ls, off);
  }
  if ((tid & 63) == 0) { sredd[tid >> 6] = (double)cep; sredd[4 + (tid >> 6)] = (double)ls; }
  __syncthreads();
  if (tid == 0) {
    double2 v;
    v.x = sredd[0] + sredd[1] + sredd[2] + sredd[3];
    v.y = sredd[4] + sredd[5] + sredd[6] + sredd[7];
    cel_part[blockIdx.x] = v;
  }
}

// Per-image sum of top-(3*n_pos) negative CEs: histogram radix-select (exact).
__global__ __launch_bounds__(256) void k_hardneg(
    const float* __restrict__ negce, const int* __restrict__ n_pos,
    double* __restrict__ hard_out)
{
  __shared__ unsigned s_bits[NPRI];     // 34928 B
  __shared__ unsigned s_hist[2048];     // 8192 B
  __shared__ unsigned s_comp[CAP];      // 8192 B
  __shared__ int s_scan[256];
  __shared__ int s_red[4];
  __shared__ double s_redd[4];
  __shared__ int s_sel[3];              // B, kp, compact counter
  const int i = blockIdx.x;
  const int tid = threadIdx.x;

  const uint4* g4 = (const uint4*)(negce + i * NPRI);
  uint4* s4 = (uint4*)s_bits;
  for (int j = tid; j < NPRI / 4; j += 256) s4[j] = g4[j];
  for (int j = tid; j < 2048; j += 256) s_hist[j] = 0u;
  __syncthreads();

  const int k = 3 * n_pos[i];
  if (k <= 0) { if (tid == 0) hard_out[i] = 0.0; return; }

  if (k >= NPRI) {   // top-k covers everything (positives are 0 in negce)
    double s = 0.0;
    for (int p = tid; p < NPRI; p += 256) s += (double)__uint_as_float(s_bits[p]);
    s = blockReduceAllDouble(s, s_redd);
    if (tid == 0) hard_out[i] = s;
    return;
  }

  // Phase A: 11-bit histogram (nonneg floats: top bits monotone in value)
  for (int p = tid; p < NPRI; p += 256) atomicAdd(&s_hist[s_bits[p] >> 20], 1u);
  __syncthreads();

  // Phase B: suffix scan over 256 groups of 8 bins -> find bin B of k-th value
  int sT = 0;
  #pragma unroll
  for (int j = 0; j < 8; ++j) sT += (int)s_hist[tid * 8 + j];
  s_scan[tid] = sT;
  __syncthreads();
  for (int off = 1; off < 256; off <<= 1) {
    const int add = (tid + off < 256) ? s_scan[tid + off] : 0;
    __syncthreads();
    s_scan[tid] += add;
    __syncthreads();
  }
  const int above_group = (tid + 1 < 256) ? s_scan[tid + 1] : 0;
  {
    int cnt_gt = above_group;
    int foundB = -1, fkp = 0;
    #pragma unroll
    for (int j = 7; j >= 0; --j) {
      const int b = tid * 8 + j;
      const int h = (int)s_hist[b];
      if (foundB < 0 && cnt_gt < k && k <= cnt_gt + h) { foundB = b; fkp = k - cnt_gt; }
      cnt_gt += h;
    }
    if (foundB >= 0) { s_sel[0] = foundB; s_sel[1] = fkp; }  // exactly one thread
  }
  if (tid == 0) s_sel[2] = 0;
  __syncthreads();
  const int B = s_sel[0];
  const int kp = s_sel[1];
  const int m = (int)s_hist[B];

  // Phase C: sum bins > B, compact bin-B elements (if they fit)
  double sg = 0.0;
  for (int p = tid; p < NPRI; p += 256) {
    const unsigned b = s_bits[p];
    const int bb = (int)(b >> 20);
    if (bb > B) sg += (double)__uint_as_float(b);
    else if (bb == B && m <= CAP) s_comp[atomicAdd(&s_sel[2], 1)] = b;
  }
  __syncthreads();

  unsigned prefix = ((unsigned)B) << 20;
  bool exact = false;
  if (m <= CAP) {
    for (int bit = 19; bit >= 0 && !exact; --bit) {
      const unsigned cand = prefix | (1u << bit);
      int cnt = 0;
      for (int p = tid; p < m; p += 256) cnt += (s_comp[p] >= cand) ? 1 : 0;
      cnt = blockReduceAllInt(cnt, s_red);
      if (cnt >= kp) prefix = cand;
      if (cnt == kp) exact = true;
    }
    int cg = 0;
    if (exact) {
      for (int p = tid; p < m; p += 256) {
        const unsigned b = s_comp[p];
        if (b >= prefix) sg += (double)__uint_as_float(b);
      }
    } else {
      for (int p = tid; p < m; p += 256) {
        const unsigned b = s_comp[p];
        if (b > prefix) { sg += (double)__uint_as_float(b); cg++; }
      }
    }
    sg = blockReduceAllDouble(sg, s_redd);
    cg = blockReduceAllInt(cg, s_red);
    if (tid == 0)
      hard_out[i] = exact ? sg
                          : sg + (double)(kp - cg) * (double)__uint_as_float(prefix);
  } else {
    // rare fallback: masked bit-search over full LDS array
    for (int bit = 19; bit >= 0 && !exact; --bit) {
      const unsigned cand = prefix | (1u << bit);
      int cnt = 0;
      for (int p = tid; p < NPRI; p += 256) {
        const unsigned b = s_bits[p];
        cnt += ((int)(b >> 20) == B && b >= cand) ? 1 : 0;
      }
      cnt = blockReduceAllInt(cnt, s_red);
      if (cnt >= kp) prefix = cand;
      if (cnt == kp) exact = true;
    }
    int cg = 0;
    for (int p = tid; p < NPRI; p += 256) {
      const unsigned b = s_bits[p];
      if ((int)(b >> 20) != B) continue;
      if (exact) { if (b >= prefix) sg += (double)__uint_as_float(b); }
      else if (b > prefix) { sg += (double)__uint_as_float(b); cg++; }
    }
    sg = blockReduceAllDouble(sg, s_redd);
    cg = blockReduceAllInt(cg, s_red);
    if (tid == 0)
      hard_out[i] = exact ? sg
                          : sg + (double)(kp - cg) * (double)__uint_as_float(prefix);
  }
}

__global__ __launch_bounds__(256) void k_final(
    const double2* __restrict__ cel_part, const double* __restrict__ hard_out,
    const int* __restrict__ n_pos, float* __restrict__ out)
{
  __shared__ double s_redd[4];
  __shared__ int s_red[4];
  const int tid = threadIdx.x;
  double ce = 0.0, ls = 0.0, hn = 0.0; int tp = 0;
  for (int j = tid; j < NP / 256; j += 256) { const double2 v = cel_part[j]; ce += v.x; ls += v.y; }
  for (int j = tid; j < NIMG; j += 256) { hn += hard_out[j]; tp += n_pos[j]; }
  ce = blockReduceAllDouble(ce, s_redd);
  ls = blockReduceAllDouble(ls, s_redd);
  hn = blockReduceAllDouble(hn, s_redd);
  tp = blockReduceAllInt(tp, s_red);
  if (tid == 0) {
    const double T = (double)tp;
    out[0] = (float)((ce + hn) / T + ls / (T * 4.0));
  }
}

// ---------------- launch ----------------

extern "C" void kernel_launch(void* const* d_in, const int* in_sizes, int n_in,
                              void* d_out, int out_size, void* d_ws, size_t ws_size,
                              hipStream_t stream)
{
  const float* locs   = (const float*)d_in[0];  // (N, P, 4)
  const float* scores = (const float*)d_in[1];  // (N, P, 21)
  const float* boxes  = (const float*)d_in[2];  // (N, 32, 4)
  const int*   labels = (const int*)d_in[3];    // (N, 32)
  const float* priors = (const float*)d_in[4];  // (P, 4)
  float* out = (float*)d_out;

  char* ws = (char*)d_ws;
  size_t off = 0;
  float*  negce  = (float*)(ws + off);  off += (size_t)NP * 4;
  int*    packed = (int*)(ws + off);    off += (size_t)NP * 4;
  float*  ovl    = (float*)(ws + off);  off += (size_t)NP * 4;
  unsigned char* obj = (unsigned char*)(ws + off); off += (size_t)NP;
  off = (off + 255) & ~(size_t)255;
  int*     pfo      = (int*)(ws + off);     off += (size_t)NIMG * NOBJ * 4;
  double2* cel_part = (double2*)(ws + off); off += (size_t)(NP / 256) * 16;
  double*  hard_out = (double*)(ws + off);  off += (size_t)NIMG * 8;
  int*     n_pos    = (int*)(ws + off);     off += (size_t)NIMG * 4;

  hipLaunchKernelGGL(k_bestobj, dim3(PCHUNKS, NIMG), dim3(256), 0, stream,
                     boxes, priors, ovl, obj);
  hipLaunchKernelGGL(k_bestpri, dim3(NIMG * 8), dim3(256), 0, stream,
                     boxes, priors, pfo);
  hipLaunchKernelGGL(k_fin, dim3(NIMG), dim3(256), 0, stream,
                     pfo, labels, ovl, obj, packed, n_pos);
  hipLaunchKernelGGL(k_celoc, dim3(NP / 256), dim3(256), 0, stream,
                     scores, locs, boxes, priors, packed, negce, cel_part);
  hipLaunchKernelGGL(k_hardneg, dim3(NIMG), dim3(256), 0, stream,
                     negce, n_pos, hard_out);
  hipLaunchKernelGGL(k_final, dim3(1), dim3(256), 0, stream,
                     cel_part, hard_out, n_pos, out);
}